// Round 13
// baseline (568.982 us; speedup 1.0000x reference)
//
#include <hip/hip_runtime.h>

#define NN 50000
#define NE 1600000
#define FILL_B 1563   // ceil((NE/4)/256)
#define EMB_B  782    // ceil((NN*4)/256)
#define HIST_STRIDE 100096 // 391 blocks * 256 threads
constexpr float LN_EPS = 1e-5f;

typedef _Float16 half8 __attribute__((ext_vector_type(8)));

__device__ __forceinline__ float gelu_f(float x){
  float ax = fabsf(x) * 0.70710678118654752440f;
  float t  = __builtin_amdgcn_rcpf(fmaf(0.3275911f, ax, 1.0f));
  float e  = __expf(-ax*ax);
  float p  = t*fmaf(t, fmaf(t, fmaf(t, fmaf(t, 1.061405429f, -1.453152027f),
                                    1.421413741f), -0.284496736f), 0.254829592f);
  float er = fmaf(-p, e, 1.0f);
  return 0.5f * x * (1.0f + copysignf(er, x));
}

__device__ __forceinline__ void ld8(const float* __restrict__ p, float* r){
  float4 a=((const float4*)p)[0], b=((const float4*)p)[1];
  r[0]=a.x;r[1]=a.y;r[2]=a.z;r[3]=a.w;r[4]=b.x;r[5]=b.y;r[6]=b.z;r[7]=b.w;
}
__device__ __forceinline__ void ld16(const float* __restrict__ p, float* r){ ld8(p,r); ld8(p+8,r+8); }
__device__ __forceinline__ void st8(float* __restrict__ p, const float* r){
  float4 a,b; a.x=r[0];a.y=r[1];a.z=r[2];a.w=r[3]; b.x=r[4];b.y=r[5];b.z=r[6];b.w=r[7];
  ((float4*)p)[0]=a; ((float4*)p)[1]=b;
}

// ---------------- hist: 16-way sharded counters, shard = blockIdx&15 ----------------
__global__ __launch_bounds__(256) void hist_kernel(const int* __restrict__ ei,
    int* __restrict__ cnt16, int* __restrict__ rank){
  int t = blockIdx.x*256 + threadIdx.x;
  int hi = (blockIdx.x & 15) << 20;
  int* mycnt = cnt16 + (size_t)(blockIdx.x & 15)*NN;
  int i0 = t, i1 = t + HIST_STRIDE, i2 = t + 2*HIST_STRIDE, i3 = t + 3*HIST_STRIDE;
  bool v0 = i0 < NE/4, v1 = i1 < NE/4, v2 = i2 < NE/4, v3 = i3 < NE/4;
  int4 d0 = v0 ? ((const int4*)(ei + NE))[i0] : make_int4(0,0,0,0);
  int4 d1 = v1 ? ((const int4*)(ei + NE))[i1] : make_int4(0,0,0,0);
  int4 d2 = v2 ? ((const int4*)(ei + NE))[i2] : make_int4(0,0,0,0);
  int4 d3 = v3 ? ((const int4*)(ei + NE))[i3] : make_int4(0,0,0,0);
  int4 r0, r1, r2, r3;
  if(v0){ r0.x = hi|atomicAdd(&mycnt[d0.x],1); r0.y = hi|atomicAdd(&mycnt[d0.y],1);
          r0.z = hi|atomicAdd(&mycnt[d0.z],1); r0.w = hi|atomicAdd(&mycnt[d0.w],1); }
  if(v1){ r1.x = hi|atomicAdd(&mycnt[d1.x],1); r1.y = hi|atomicAdd(&mycnt[d1.y],1);
          r1.z = hi|atomicAdd(&mycnt[d1.z],1); r1.w = hi|atomicAdd(&mycnt[d1.w],1); }
  if(v2){ r2.x = hi|atomicAdd(&mycnt[d2.x],1); r2.y = hi|atomicAdd(&mycnt[d2.y],1);
          r2.z = hi|atomicAdd(&mycnt[d2.z],1); r2.w = hi|atomicAdd(&mycnt[d2.w],1); }
  if(v3){ r3.x = hi|atomicAdd(&mycnt[d3.x],1); r3.y = hi|atomicAdd(&mycnt[d3.y],1);
          r3.z = hi|atomicAdd(&mycnt[d3.z],1); r3.w = hi|atomicAdd(&mycnt[d3.w],1); }
  if(v0) ((int4*)rank)[i0] = r0;
  if(v1) ((int4*)rank)[i1] = r1;
  if(v2) ((int4*)rank)[i2] = r2;
  if(v3) ((int4*)rank)[i3] = r3;
}

// ---------------- reduce16: per-node shard prefix (in place) + deg ----------------
__global__ __launch_bounds__(256) void reduce16_kernel(int* __restrict__ cnt16,
    int* __restrict__ deg){
  int n = blockIdx.x*256 + threadIdx.x;
  if(n >= NN) return;
  int run = 0;
  #pragma unroll
  for(int x=0;x<16;x++){
    int c = cnt16[(size_t)x*NN + n];
    cnt16[(size_t)x*NN + n] = run;
    run += c;
  }
  deg[n] = run;
}

#define CHUNK 52
__global__ __launch_bounds__(1024) void scan_kernel(const int* __restrict__ deg, int* __restrict__ row_ptr){
  __shared__ int sums[1024];
  int t = threadIdx.x;
  int base = t*CHUNK;
  int4 v[13];
  int ssum = 0;
  #pragma unroll
  for(int i=0;i<13;i++){
    int idx = base + 4*i;
    if(idx + 3 < NN){
      v[i] = ((const int4*)deg)[(base>>2)+i];
    } else {
      v[i].x = (idx+0<NN)?deg[idx+0]:0; v[i].y = (idx+1<NN)?deg[idx+1]:0;
      v[i].z = (idx+2<NN)?deg[idx+2]:0; v[i].w = (idx+3<NN)?deg[idx+3]:0;
    }
    ssum += v[i].x + v[i].y + v[i].z + v[i].w;
  }
  sums[t]=ssum;
  __syncthreads();
  for(int off=1; off<1024; off<<=1){
    int vv = (t>=off) ? sums[t-off] : 0;
    __syncthreads();
    sums[t] += vv;
    __syncthreads();
  }
  int run = (t>0) ? sums[t-1] : 0;
  #pragma unroll
  for(int i=0;i<13;i++){
    int idx = base + 4*i;
    int4 o;
    o.x = run; run += v[i].x;
    o.y = run; run += v[i].y;
    o.z = run; run += v[i].z;
    o.w = run; run += v[i].w;
    if(idx + 3 < NN){
      ((int4*)row_ptr)[(base>>2)+i] = o;
    } else {
      if(idx+0<NN) row_ptr[idx+0]=o.x;
      if(idx+1<NN) row_ptr[idx+1]=o.y;
      if(idx+2<NN) row_ptr[idx+2]=o.z;
      if(idx+3<NN) row_ptr[idx+3]=o.w;
    }
  }
  if(t==1023) row_ptr[NN] = sums[1023];
}

// ---------------- addbase16: base16[x][n] = row_ptr[n] + offs16[x][n] ----------------
__global__ __launch_bounds__(256) void addbase16_kernel(int* __restrict__ cnt16,
    const int* __restrict__ row_ptr){
  int t = blockIdx.x*256 + threadIdx.x;
  if(t >= 16*(NN/4)) return;
  int x  = t / (NN/4);
  int n4 = t - x*(NN/4);
  int4 rp = ((const int4*)row_ptr)[n4];
  int4 c  = ((int4*)(cnt16 + (size_t)x*NN))[n4];
  c.x += rp.x; c.y += rp.y; c.z += rp.z; c.w += rp.w;
  ((int4*)(cnt16 + (size_t)x*NN))[n4] = c;
}

// ---------------- fused: embed+PQR0 (blocks 0..EMB_B) || fill (rest) ----------------
__global__ __launch_bounds__(256) void fill_embed_kernel(
    const int* __restrict__ ei,
    const int* __restrict__ rank, const int* __restrict__ base16,
    int* __restrict__ csr,
    const float* __restrict__ x,
    const float* __restrict__ W1, const float* __restrict__ b1,
    const float* __restrict__ g1, const float* __restrict__ bb1,
    const float* __restrict__ W2, const float* __restrict__ b2,
    const float* __restrict__ g2, const float* __restrict__ bb2,
    const float* __restrict__ Wm, const float* __restrict__ bm,
    const float* __restrict__ Wu, const float* __restrict__ bu,
    const float* __restrict__ fb1, const float* __restrict__ fbng, const float* __restrict__ fbnb,
    float* __restrict__ h, float* __restrict__ pre,
    float* __restrict__ P, _Float16* __restrict__ Qh, float* __restrict__ R,
    float* __restrict__ cvec)
{
  if(blockIdx.x >= EMB_B){
    int t = (blockIdx.x - EMB_B)*256 + threadIdx.x;
    if(t < NE/4){
      int4 d  = ((const int4*)(ei + NE))[t];
      int4 sv = ((const int4*)ei)[t];
      int4 rk = ((const int4*)rank)[t];
      csr[base16[(size_t)((unsigned)rk.x>>20)*NN + d.x] + (rk.x & 0xFFFFF)] = sv.x;
      csr[base16[(size_t)((unsigned)rk.y>>20)*NN + d.y] + (rk.y & 0xFFFFF)] = sv.y;
      csr[base16[(size_t)((unsigned)rk.z>>20)*NN + d.z] + (rk.z & 0xFFFFF)] = sv.z;
      csr[base16[(size_t)((unsigned)rk.w>>20)*NN + d.w] + (rk.w & 0xFFFFF)] = sv.w;
    }
    return;
  }
  int t = blockIdx.x*256 + threadIdx.x;
  const float rs = rsqrtf(1.0f + LN_EPS);
  if(t < 64) cvec[t] = fmaf(fb1[t], fbng[t]*rs, fbnb[t]);
  int n = t >> 2, q = t & 3;
  if(n >= NN) return;
  int base = threadIdx.x & 60;
  float4 xq = ((const float4*)x)[n*4 + q];
  float xv[16];
  #pragma unroll
  for(int m=0;m<4;m++){
    xv[4*m+0]=__shfl(xq.x, base|m);
    xv[4*m+1]=__shfl(xq.y, base|m);
    xv[4*m+2]=__shfl(xq.z, base|m);
    xv[4*m+3]=__shfl(xq.w, base|m);
  }
  float a1q[16]; ld16(b1 + q*16, a1q);
  #pragma unroll
  for(int k=0;k<16;k++){
    float w[16]; ld16(W1 + k*64 + q*16, w);
    float xk = xv[k];
    #pragma unroll
    for(int j=0;j<16;j++) a1q[j] += xk * w[j];
  }
  { float g[16], b[16]; ld16(g1+q*16,g); ld16(bb1+q*16,b);
    #pragma unroll
    for(int j=0;j<16;j++) a1q[j] = gelu_f(a1q[j]*(g[j]*rs) + b[j]); }
  float hq[8]; ld8(b2 + q*8, hq);
  #pragma unroll
  for(int m=0;m<4;m++){
    #pragma unroll
    for(int kk=0;kk<16;kk++){
      float a = __shfl(a1q[kk], base|m);
      float w[8]; ld8(W2 + (m*16+kk)*32 + q*8, w);
      #pragma unroll
      for(int j=0;j<8;j++) hq[j] += a * w[j];
    }
  }
  { float g[8], b[8]; ld8(g2+q*8,g); ld8(bb2+q*8,b);
    #pragma unroll
    for(int j=0;j<8;j++) hq[j] = gelu_f(hq[j]*(g[j]*rs) + b[j]); }
  st8(h   + (size_t)n*32 + q*8, hq);
  st8(pre + (size_t)n*32 + q*8, hq);
  float apv[8], aqv[8], arv[8];
  ld8(bm+q*8, apv); ld8(bu+q*8, arv);
  #pragma unroll
  for(int j=0;j<8;j++) aqv[j]=0.f;
  #pragma unroll
  for(int m=0;m<4;m++){
    #pragma unroll
    for(int kk=0;kk<8;kk++){
      float hk = __shfl(hq[kk], base|m);
      int k = m*8+kk;
      float wm[8],wq[8],wu[8];
      ld8(Wm + k*32      + q*8, wm);
      ld8(Wm + (32+k)*32 + q*8, wq);
      ld8(Wu + k*32      + q*8, wu);
      #pragma unroll
      for(int j=0;j<8;j++){ apv[j]+=hk*wm[j]; aqv[j]+=hk*wq[j]; arv[j]+=hk*wu[j]; }
    }
  }
  st8(P + (size_t)n*32 + q*8, apv);
  st8(R + (size_t)n*32 + q*8, arv);
  half8 qo;
  #pragma unroll
  for(int k=0;k<8;k++) qo[k] = (_Float16)aqv[k];
  *(half8*)(Qh + (size_t)n*32 + q*8) = qo;
}

// -------- message+aggregate: EDGE PER LANE, in-lane LN, reduce-scatter to feature-l --------
__global__ __launch_bounds__(256) void msg_kernel(
    const float* __restrict__ P, const _Float16* __restrict__ Qh,
    const int* __restrict__ row_ptr, const int* __restrict__ csr_src,
    const float* __restrict__ mg, const float* __restrict__ mb,
    float* __restrict__ aggO)
{
  int tid = blockIdx.x*256 + threadIdx.x;   // grid = NN*32 exactly
  int n = tid >> 5;
  int lane = tid & 31;
  float mgv[32], mbv[32], p[32];
  ld16(mg, mgv); ld16(mg+16, mgv+16);      // grid-uniform -> SGPR
  ld16(mb, mbv); ld16(mb+16, mbv+16);
  ld16(P + (size_t)n*32, p); ld16(P + (size_t)n*32 + 16, p+16);
  float agg[32];
  #pragma unroll
  for(int j=0;j<32;j++) agg[j]=0.f;
  int e0 = row_ptr[n], e1 = row_ptr[n+1];
  for(int e = e0 + lane; e < e1; e += 32){
    int src = csr_src[e];                  // coalesced across lanes
    const half8* q4 = (const half8*)(Qh + (size_t)src*32);
    half8 q0=q4[0], q1=q4[1], q2=q4[2], q3=q4[3];
    float v[32];
    #pragma unroll
    for(int k=0;k<8;k++){
      v[k]    = p[k]    + (float)q0[k];
      v[8+k]  = p[8+k]  + (float)q1[k];
      v[16+k] = p[16+k] + (float)q2[k];
      v[24+k] = p[24+k] + (float)q3[k];
    }
    float s0=0,s1=0,s2=0,s3=0;
    #pragma unroll
    for(int i=0;i<8;i++){ s0+=v[4*i]; s1+=v[4*i+1]; s2+=v[4*i+2]; s3+=v[4*i+3]; }
    float mean = ((s0+s1)+(s2+s3)) * 0.03125f;
    s0=s1=s2=s3=0.f;
    #pragma unroll
    for(int i=0;i<8;i++){
      float d0=v[4*i]-mean, d1=v[4*i+1]-mean, d2=v[4*i+2]-mean, d3=v[4*i+3]-mean;
      s0+=d0*d0; s1+=d1*d1; s2+=d2*d2; s3+=d3*d3;
      v[4*i]=d0; v[4*i+1]=d1; v[4*i+2]=d2; v[4*i+3]=d3;
    }
    float rstd = rsqrtf(((s0+s1)+(s2+s3))*0.03125f + LN_EPS);
    #pragma unroll
    for(int j=0;j<32;j++) agg[j] += gelu_f(v[j]*rstd*mgv[j] + mbv[j]);
  }
  // reduce-scatter over 32 lanes: lane l ends with feature l summed over all lanes
  float r16[16];
  { int up = lane & 16;
    #pragma unroll
    for(int j=0;j<16;j++){
      float mine   = up ? agg[16+j] : agg[j];
      float theirs = up ? agg[j]    : agg[16+j];
      r16[j] = mine + __shfl_xor(theirs, 16);
    } }
  float r8[8];
  { int up = lane & 8;
    #pragma unroll
    for(int j=0;j<8;j++){
      float mine   = up ? r16[8+j] : r16[j];
      float theirs = up ? r16[j]   : r16[8+j];
      r8[j] = mine + __shfl_xor(theirs, 8);
    } }
  float r4[4];
  { int up = lane & 4;
    #pragma unroll
    for(int j=0;j<4;j++){
      float mine   = up ? r8[4+j] : r8[j];
      float theirs = up ? r8[j]   : r8[4+j];
      r4[j] = mine + __shfl_xor(theirs, 4);
    } }
  float r2[2];
  { int up = lane & 2;
    #pragma unroll
    for(int j=0;j<2;j++){
      float mine   = up ? r4[2+j] : r4[j];
      float theirs = up ? r4[j]   : r4[2+j];
      r2[j] = mine + __shfl_xor(theirs, 2);
    } }
  float r1;
  { int up = lane & 1;
    float mine   = up ? r2[1] : r2[0];
    float theirs = up ? r2[0] : r2[1];
    r1 = mine + __shfl_xor(theirs, 1);
  }
  aggO[(size_t)n*32 + lane] = r1;   // contiguous 128B per node
}

// -------- update MLP + next-layer PQR, 4 lanes/node --------
__global__ __launch_bounds__(256) void upd_pqr_kernel(
    const float* __restrict__ aggI, const float* __restrict__ Rio,
    const float* __restrict__ Ub,
    const float* __restrict__ ug, const float* __restrict__ ub,
    const float* __restrict__ Wm2, const float* __restrict__ bm2,
    const float* __restrict__ Wu2, const float* __restrict__ bu2,
    float* __restrict__ h,
    float* __restrict__ P, _Float16* __restrict__ Qh, float* __restrict__ Rout)
{
  int t = blockIdx.x*256 + threadIdx.x;
  int n = t >> 2, q = t & 3;
  if(n >= NN) return;
  int base = threadIdx.x & 60;
  float aggq[8], uq[8];
  ld8(aggI + (size_t)n*32 + q*8, aggq);
  ld8(Rio  + (size_t)n*32 + q*8, uq);
  #pragma unroll
  for(int m=0;m<4;m++){
    #pragma unroll
    for(int kk=0;kk<8;kk++){
      float a = __shfl(aggq[kk], base|m);
      float w[8]; ld8(Ub + (m*8+kk)*32 + q*8, w);
      #pragma unroll
      for(int j=0;j<8;j++) uq[j] += a * w[j];
    }
  }
  float sm = ((uq[0]+uq[1])+(uq[2]+uq[3])) + ((uq[4]+uq[5])+(uq[6]+uq[7]));
  sm += __shfl_xor(sm,1); sm += __shfl_xor(sm,2);
  float mean = sm * 0.03125f;
  float vs = 0.f;
  #pragma unroll
  for(int j=0;j<8;j++){ float d = uq[j]-mean; vs += d*d; uq[j]=d; }
  vs += __shfl_xor(vs,1); vs += __shfl_xor(vs,2);
  float rstd = rsqrtf(vs*0.03125f + LN_EPS);
  float ugq[8], ubq[8], hq[8];
  ld8(ug+q*8, ugq); ld8(ub+q*8, ubq);
  ld8(h + (size_t)n*32 + q*8, hq);
  #pragma unroll
  for(int j=0;j<8;j++) hq[j] += gelu_f(uq[j]*rstd*ugq[j] + ubq[j]);
  st8(h + (size_t)n*32 + q*8, hq);
  // next-layer PQR
  float apv[8], aqv[8], arv[8];
  ld8(bm2+q*8, apv); ld8(bu2+q*8, arv);
  #pragma unroll
  for(int j=0;j<8;j++) aqv[j]=0.f;
  #pragma unroll
  for(int m=0;m<4;m++){
    #pragma unroll
    for(int kk=0;kk<8;kk++){
      float hk = __shfl(hq[kk], base|m);
      int k = m*8+kk;
      float wm[8],wq[8],wu[8];
      ld8(Wm2 + k*32      + q*8, wm);
      ld8(Wm2 + (32+k)*32 + q*8, wq);
      ld8(Wu2 + k*32      + q*8, wu);
      #pragma unroll
      for(int j=0;j<8;j++){ apv[j]+=hk*wm[j]; aqv[j]+=hk*wq[j]; arv[j]+=hk*wu[j]; }
    }
  }
  st8(P    + (size_t)n*32 + q*8, apv);
  st8(Rout + (size_t)n*32 + q*8, arv);
  half8 qo;
  #pragma unroll
  for(int k=0;k<8;k++) qo[k] = (_Float16)aqv[k];
  *(half8*)(Qh + (size_t)n*32 + q*8) = qo;
}

// -------- last update + final node matmul, 4 lanes/node, split-half fp16 y --------
__global__ __launch_bounds__(256) void upd_fin_kernel(
    const float* __restrict__ aggI, const float* __restrict__ Rio,
    const float* __restrict__ Ub,
    const float* __restrict__ ug, const float* __restrict__ ub,
    const float* __restrict__ h, const float* __restrict__ pre,
    const float* __restrict__ fW1, const float* __restrict__ fbng,
    _Float16* __restrict__ y1, _Float16* __restrict__ y2)
{
  int t = blockIdx.x*256 + threadIdx.x;
  int n = t >> 2, q = t & 3;
  if(n >= NN) return;
  int base = threadIdx.x & 60;
  const float rs = rsqrtf(1.0f + LN_EPS);
  float aggq[8], uq[8];
  ld8(aggI + (size_t)n*32 + q*8, aggq);
  ld8(Rio  + (size_t)n*32 + q*8, uq);
  #pragma unroll
  for(int m=0;m<4;m++){
    #pragma unroll
    for(int kk=0;kk<8;kk++){
      float a = __shfl(aggq[kk], base|m);
      float w[8]; ld8(Ub + (m*8+kk)*32 + q*8, w);
      #pragma unroll
      for(int j=0;j<8;j++) uq[j] += a * w[j];
    }
  }
  float sm = ((uq[0]+uq[1])+(uq[2]+uq[3])) + ((uq[4]+uq[5])+(uq[6]+uq[7]));
  sm += __shfl_xor(sm,1); sm += __shfl_xor(sm,2);
  float mean = sm * 0.03125f;
  float vs = 0.f;
  #pragma unroll
  for(int j=0;j<8;j++){ float d = uq[j]-mean; vs += d*d; uq[j]=d; }
  vs += __shfl_xor(vs,1); vs += __shfl_xor(vs,2);
  float rstd = rsqrtf(vs*0.03125f + LN_EPS);
  float ugq[8], ubq[8], hq[8], pq[8];
  ld8(ug+q*8, ugq); ld8(ub+q*8, ubq);
  ld8(h   + (size_t)n*32 + q*8, hq);
  ld8(pre + (size_t)n*32 + q*8, pq);
  #pragma unroll
  for(int j=0;j<8;j++) hq[j] += gelu_f(uq[j]*rstd*ugq[j] + ubq[j]) + pq[j];
  float acc[16];
  #pragma unroll
  for(int j=0;j<16;j++) acc[j]=0.f;
  #pragma unroll
  for(int m=0;m<4;m++){
    #pragma unroll
    for(int kk=0;kk<8;kk++){
      float hk = __shfl(hq[kk], base|m);
      float w[16]; ld16(fW1 + (m*8+kk)*64 + q*16, w);
      #pragma unroll
      for(int j=0;j<16;j++) acc[j] += hk * w[j];
    }
  }
  float fg[16]; ld16(fbng + q*16, fg);
  half8 o0, o1;
  #pragma unroll
  for(int k=0;k<8;k++){
    o0[k] = (_Float16)(acc[k]   * (fg[k]*rs));
    o1[k] = (_Float16)(acc[8+k] * (fg[8+k]*rs));
  }
  _Float16* dst = (q<2) ? (y1 + (size_t)n*32 + q*16) : (y2 + (size_t)n*32 + (q-2)*16);
  ((half8*)dst)[0] = o0; ((half8*)dst)[1] = o1;
}

// ---------------- final per-edge: 4 lanes per edge, 2 edges/group, feature-split ----------------
__global__ __launch_bounds__(256) void finalA_kernel(
    const _Float16* __restrict__ y, const int* __restrict__ ei,
    const float* __restrict__ cvec, const float* __restrict__ W2,
    const float* __restrict__ b2, float* __restrict__ out)
{
  int t = blockIdx.x*256 + threadIdx.x;   // grid = NE*2 exactly
  int g = t >> 2, q = t & 3;
  int eA = g, eB = g + NE/2;
  int sA = __builtin_nontemporal_load(ei + eA);
  int dA = __builtin_nontemporal_load(ei + NE + eA);
  int sB = __builtin_nontemporal_load(ei + eB);
  int dB = __builtin_nontemporal_load(ei + NE + eB);
  half8 aA = *(const half8*)(y + (size_t)dA*32 + q*8);
  half8 cA = *(const half8*)(y + (size_t)sA*32 + q*8);
  half8 aB = *(const half8*)(y + (size_t)dB*32 + q*8);
  half8 cB = *(const half8*)(y + (size_t)sB*32 + q*8);
  float cq[8]; ld8(cvec + q*8, cq);
  float w[24]; ld8(W2+q*24, w); ld8(W2+q*24+8, w+8); ld8(W2+q*24+16, w+16);
  float oA0=0.f,oA1=0.f,oA2=0.f, oB0=0.f,oB1=0.f,oB2=0.f;
  #pragma unroll
  for(int k=0;k<8;k++){
    float tA = gelu_f(((float)aA[k]-(float)cA[k]) + cq[k]);
    float tB = gelu_f(((float)aB[k]-(float)cB[k]) + cq[k]);
    oA0 += tA*w[3*k]; oA1 += tA*w[3*k+1]; oA2 += tA*w[3*k+2];
    oB0 += tB*w[3*k]; oB1 += tB*w[3*k+1]; oB2 += tB*w[3*k+2];
  }
  oA0 += __shfl_xor(oA0,1); oA0 += __shfl_xor(oA0,2);
  oA1 += __shfl_xor(oA1,1); oA1 += __shfl_xor(oA1,2);
  oA2 += __shfl_xor(oA2,1); oA2 += __shfl_xor(oA2,2);
  oB0 += __shfl_xor(oB0,1); oB0 += __shfl_xor(oB0,2);
  oB1 += __shfl_xor(oB1,1); oB1 += __shfl_xor(oB1,2);
  oB2 += __shfl_xor(oB2,1); oB2 += __shfl_xor(oB2,2);
  float ovA = (q==0) ? oA0 + b2[0] : (q==1) ? oA1 + b2[1] : oA2 + b2[2];
  float ovB = (q==0) ? oB0 + b2[0] : (q==1) ? oB1 + b2[1] : oB2 + b2[2];
  if(q < 3){
    __builtin_nontemporal_store(ovA, out + (size_t)eA*3 + q);
    __builtin_nontemporal_store(ovB, out + (size_t)eB*3 + q);
  }
}

__global__ __launch_bounds__(256) void finalB_kernel(
    const _Float16* __restrict__ y, const int* __restrict__ ei,
    const float* __restrict__ cvec, const float* __restrict__ W2,
    float* __restrict__ out)
{
  int t = blockIdx.x*256 + threadIdx.x;
  int g = t >> 2, q = t & 3;
  int eA = g, eB = g + NE/2;
  float pA = 0.f, pB = 0.f;
  if(q < 3){
    pA = __builtin_nontemporal_load(out + (size_t)eA*3 + q);
    pB = __builtin_nontemporal_load(out + (size_t)eB*3 + q);
  }
  int sA = __builtin_nontemporal_load(ei + eA);
  int dA = __builtin_nontemporal_load(ei + NE + eA);
  int sB = __builtin_nontemporal_load(ei + eB);
  int dB = __builtin_nontemporal_load(ei + NE + eB);
  half8 aA = *(const half8*)(y + (size_t)dA*32 + q*8);
  half8 cA = *(const half8*)(y + (size_t)sA*32 + q*8);
  half8 aB = *(const half8*)(y + (size_t)dB*32 + q*8);
  half8 cB = *(const half8*)(y + (size_t)sB*32 + q*8);
  float cq[8]; ld8(cvec + q*8, cq);
  float w[24]; ld8(W2+q*24, w); ld8(W2+q*24+8, w+8); ld8(W2+q*24+16, w+16);
  float oA0=0.f,oA1=0.f,oA2=0.f, oB0=0.f,oB1=0.f,oB2=0.f;
  #pragma unroll
  for(int k=0;k<8;k++){
    float tA = gelu_f(((float)aA[k]-(float)cA[k]) + cq[k]);
    float tB = gelu_f(((float)aB[k]-(float)cB[k]) + cq[k]);
    oA0 += tA*w[3*k]; oA1 += tA*w[3*k+1]; oA2 += tA*w[3*k+2];
    oB0 += tB*w[3*k]; oB1 += tB*w[3*k+1]; oB2 += tB*w[3*k+2];
  }
  oA0 += __shfl_xor(oA0,1); oA0 += __shfl_xor(oA0,2);
  oA1 += __shfl_xor(oA1,1); oA1 += __shfl_xor(oA1,2);
  oA2 += __shfl_xor(oA2,1); oA2 += __shfl_xor(oA2,2);
  oB0 += __shfl_xor(oB0,1); oB0 += __shfl_xor(oB0,2);
  oB1 += __shfl_xor(oB1,1); oB1 += __shfl_xor(oB1,2);
  oB2 += __shfl_xor(oB2,1); oB2 += __shfl_xor(oB2,2);
  float ovA = pA + ((q==0) ? oA0 : (q==1) ? oA1 : oA2);
  float ovB = pB + ((q==0) ? oB0 : (q==1) ? oB1 : oB2);
  if(q < 3){
    __builtin_nontemporal_store(ovA, out + (size_t)eA*3 + q);
    __builtin_nontemporal_store(ovB, out + (size_t)eB*3 + q);
  }
}

extern "C" void kernel_launch(void* const* d_in, const int* in_sizes, int n_in,
                              void* d_out, int out_size, void* d_ws, size_t ws_size,
                              hipStream_t stream)
{
  (void)in_sizes; (void)n_in; (void)out_size; (void)ws_size;
  const float* x     = (const float*)d_in[0];
  const int*   ei    = (const int*)d_in[1];
  const float* eW1   = (const float*)d_in[2];
  const float* eb1   = (const float*)d_in[3];
  const float* ebn1g = (const float*)d_in[4];
  const float* ebn1b = (const float*)d_in[5];
  const float* eW2   = (const float*)d_in[6];
  const float* eb2   = (const float*)d_in[7];
  const float* ebn2g = (const float*)d_in[8];
  const float* ebn2b = (const float*)d_in[9];
  const float* msgW  = (const float*)d_in[10];
  const float* msgb  = (const float*)d_in[11];
  const float* msglng= (const float*)d_in[12];
  const float* msglnb= (const float*)d_in[13];
  const float* updW  = (const float*)d_in[14];
  const float* updb  = (const float*)d_in[15];
  const float* updlng= (const float*)d_in[16];
  const float* updlnb= (const float*)d_in[17];
  const float* fW1   = (const float*)d_in[18];
  const float* fb1   = (const float*)d_in[19];
  const float* fbng  = (const float*)d_in[20];
  const float* fbnb  = (const float*)d_in[21];
  const float* fW2   = (const float*)d_in[22];
  const float* fb2   = (const float*)d_in[23];
  float* out = (float*)d_out;

  // workspace: h, pre, P, R, agg (NN*32 f32 each), Qh (NN*16 f32), cvec, ints
  float* f   = (float*)d_ws;
  float* h   = f;
  float* pre = f + 1*(size_t)NN*32;
  float* P   = f + 2*(size_t)NN*32;
  float* R   = f + 3*(size_t)NN*32;
  float* agg = f + 4*(size_t)NN*32;
  _Float16* Qh = (_Float16*)(f + 5*(size_t)NN*32);   // NN*32 halves
  _Float16* y1 = (_Float16*)P;                        // NN*32 halves (P dead after msg2)
  _Float16* y2 = y1 + (size_t)NN*32;                  // NN*32 halves (still within P)
  float* cvec  = f + 5*(size_t)NN*32 + (size_t)NN*16; // 64 floats
  int* ip      = (int*)(cvec + 64);
  int* cnt16   = ip;                  // 16*NN (shard-prefix, then base16 after addbase16)
  int* deg     = ip + 16*NN;          // NN
  int* row_ptr = ip + 17*NN;          // NN+4
  int* csr     = ip + 18*NN + 4;      // NE
  int* rank    = (int*)agg;           // NE ints, aliases agg (free until msg layer 0)

  hipMemsetAsync(cnt16, 0, (size_t)16*NN*sizeof(int), stream);
  hist_kernel<<<391, 256, 0, stream>>>(ei, cnt16, rank);
  reduce16_kernel<<<(NN+255)/256, 256, 0, stream>>>(cnt16, deg);
  scan_kernel<<<1, 1024, 0, stream>>>(deg, row_ptr);
  addbase16_kernel<<<(16*(NN/4)+255)/256, 256, 0, stream>>>(cnt16, row_ptr);
  fill_embed_kernel<<<EMB_B + FILL_B, 256, 0, stream>>>(ei, rank, cnt16, csr,
      x, eW1, eb1, ebn1g, ebn1b,
      eW2, eb2, ebn2g, ebn2b,
      msgW, msgb, updW, updb,
      fb1, fbng, fbnb,
      h, pre, P, Qh, R, cvec);

  for(int l=0; l<3; l++){
    msg_kernel<<<(NN*32)/256, 256, 0, stream>>>(P, Qh, row_ptr, csr,
        msglng + l*32, msglnb + l*32, agg);
    if(l < 2){
      upd_pqr_kernel<<<EMB_B, 256, 0, stream>>>(agg, R,
          updW + l*2048 + 1024, updlng + l*32, updlnb + l*32,
          msgW + (l+1)*2048, msgb + (l+1)*32,
          updW + (l+1)*2048, updb + (l+1)*32,
          h, P, Qh, R);
    } else {
      upd_fin_kernel<<<EMB_B, 256, 0, stream>>>(agg, R,
          updW + l*2048 + 1024, updlng + l*32, updlnb + l*32,
          h, pre, fW1, fbng, y1, y2);
    }
  }

  finalA_kernel<<<(NE*2)/256, 256, 0, stream>>>(y1, ei, cvec,      fW2,      fb2, out);
  finalB_kernel<<<(NE*2)/256, 256, 0, stream>>>(y2, ei, cvec + 32, fW2 + 96, out);
}

// Round 15
// 492.217 us; speedup vs baseline: 1.1560x; 1.1560x over previous
//
#include <hip/hip_runtime.h>

#define NN 50000
#define NE 1600000
#define FILL_B 1563   // ceil((NE/4)/256)
#define EMB_B  782    // ceil((NN*4)/256)
#define HIST_STRIDE 100096 // 391 blocks * 256 threads
constexpr float LN_EPS = 1e-5f;

typedef _Float16 half8 __attribute__((ext_vector_type(8)));

__device__ __forceinline__ float gelu_f(float x){
  float ax = fabsf(x) * 0.70710678118654752440f;
  float t  = __builtin_amdgcn_rcpf(fmaf(0.3275911f, ax, 1.0f));
  float e  = __expf(-ax*ax);
  float p  = t*fmaf(t, fmaf(t, fmaf(t, fmaf(t, 1.061405429f, -1.453152027f),
                                    1.421413741f), -0.284496736f), 0.254829592f);
  float er = fmaf(-p, e, 1.0f);
  return 0.5f * x * (1.0f + copysignf(er, x));
}

__device__ __forceinline__ void ld8(const float* __restrict__ p, float* r){
  float4 a=((const float4*)p)[0], b=((const float4*)p)[1];
  r[0]=a.x;r[1]=a.y;r[2]=a.z;r[3]=a.w;r[4]=b.x;r[5]=b.y;r[6]=b.z;r[7]=b.w;
}
__device__ __forceinline__ void ld16(const float* __restrict__ p, float* r){ ld8(p,r); ld8(p+8,r+8); }
__device__ __forceinline__ void st8(float* __restrict__ p, const float* r){
  float4 a,b; a.x=r[0];a.y=r[1];a.z=r[2];a.w=r[3]; b.x=r[4];b.y=r[5];b.z=r[6];b.w=r[7];
  ((float4*)p)[0]=a; ((float4*)p)[1]=b;
}

// ---------------- hist: 16-way sharded counters, shard = blockIdx&15 ----------------
__global__ __launch_bounds__(256) void hist_kernel(const int* __restrict__ ei,
    int* __restrict__ cnt16, int* __restrict__ rank){
  int t = blockIdx.x*256 + threadIdx.x;
  int hi = (blockIdx.x & 15) << 20;
  int* mycnt = cnt16 + (size_t)(blockIdx.x & 15)*NN;
  int i0 = t, i1 = t + HIST_STRIDE, i2 = t + 2*HIST_STRIDE, i3 = t + 3*HIST_STRIDE;
  bool v0 = i0 < NE/4, v1 = i1 < NE/4, v2 = i2 < NE/4, v3 = i3 < NE/4;
  int4 d0 = v0 ? ((const int4*)(ei + NE))[i0] : make_int4(0,0,0,0);
  int4 d1 = v1 ? ((const int4*)(ei + NE))[i1] : make_int4(0,0,0,0);
  int4 d2 = v2 ? ((const int4*)(ei + NE))[i2] : make_int4(0,0,0,0);
  int4 d3 = v3 ? ((const int4*)(ei + NE))[i3] : make_int4(0,0,0,0);
  int4 r0, r1, r2, r3;
  if(v0){ r0.x = hi|atomicAdd(&mycnt[d0.x],1); r0.y = hi|atomicAdd(&mycnt[d0.y],1);
          r0.z = hi|atomicAdd(&mycnt[d0.z],1); r0.w = hi|atomicAdd(&mycnt[d0.w],1); }
  if(v1){ r1.x = hi|atomicAdd(&mycnt[d1.x],1); r1.y = hi|atomicAdd(&mycnt[d1.y],1);
          r1.z = hi|atomicAdd(&mycnt[d1.z],1); r1.w = hi|atomicAdd(&mycnt[d1.w],1); }
  if(v2){ r2.x = hi|atomicAdd(&mycnt[d2.x],1); r2.y = hi|atomicAdd(&mycnt[d2.y],1);
          r2.z = hi|atomicAdd(&mycnt[d2.z],1); r2.w = hi|atomicAdd(&mycnt[d2.w],1); }
  if(v3){ r3.x = hi|atomicAdd(&mycnt[d3.x],1); r3.y = hi|atomicAdd(&mycnt[d3.y],1);
          r3.z = hi|atomicAdd(&mycnt[d3.z],1); r3.w = hi|atomicAdd(&mycnt[d3.w],1); }
  if(v0) ((int4*)rank)[i0] = r0;
  if(v1) ((int4*)rank)[i1] = r1;
  if(v2) ((int4*)rank)[i2] = r2;
  if(v3) ((int4*)rank)[i3] = r3;
}

// ---------------- reduce16: per-node shard prefix (in place) + deg ----------------
__global__ __launch_bounds__(256) void reduce16_kernel(int* __restrict__ cnt16,
    int* __restrict__ deg){
  int n = blockIdx.x*256 + threadIdx.x;
  if(n >= NN) return;
  int run = 0;
  #pragma unroll
  for(int x=0;x<16;x++){
    int c = cnt16[(size_t)x*NN + n];
    cnt16[(size_t)x*NN + n] = run;
    run += c;
  }
  deg[n] = run;
}

#define CHUNK 52
__global__ __launch_bounds__(1024) void scan_kernel(const int* __restrict__ deg, int* __restrict__ row_ptr){
  __shared__ int sums[1024];
  int t = threadIdx.x;
  int base = t*CHUNK;
  int4 v[13];
  int ssum = 0;
  #pragma unroll
  for(int i=0;i<13;i++){
    int idx = base + 4*i;
    if(idx + 3 < NN){
      v[i] = ((const int4*)deg)[(base>>2)+i];
    } else {
      v[i].x = (idx+0<NN)?deg[idx+0]:0; v[i].y = (idx+1<NN)?deg[idx+1]:0;
      v[i].z = (idx+2<NN)?deg[idx+2]:0; v[i].w = (idx+3<NN)?deg[idx+3]:0;
    }
    ssum += v[i].x + v[i].y + v[i].z + v[i].w;
  }
  sums[t]=ssum;
  __syncthreads();
  for(int off=1; off<1024; off<<=1){
    int vv = (t>=off) ? sums[t-off] : 0;
    __syncthreads();
    sums[t] += vv;
    __syncthreads();
  }
  int run = (t>0) ? sums[t-1] : 0;
  #pragma unroll
  for(int i=0;i<13;i++){
    int idx = base + 4*i;
    int4 o;
    o.x = run; run += v[i].x;
    o.y = run; run += v[i].y;
    o.z = run; run += v[i].z;
    o.w = run; run += v[i].w;
    if(idx + 3 < NN){
      ((int4*)row_ptr)[(base>>2)+i] = o;
    } else {
      if(idx+0<NN) row_ptr[idx+0]=o.x;
      if(idx+1<NN) row_ptr[idx+1]=o.y;
      if(idx+2<NN) row_ptr[idx+2]=o.z;
      if(idx+3<NN) row_ptr[idx+3]=o.w;
    }
  }
  if(t==1023) row_ptr[NN] = sums[1023];
}

// ---------------- addbase16: base16[x][n] = row_ptr[n] + offs16[x][n] ----------------
__global__ __launch_bounds__(256) void addbase16_kernel(int* __restrict__ cnt16,
    const int* __restrict__ row_ptr){
  int t = blockIdx.x*256 + threadIdx.x;
  if(t >= 16*(NN/4)) return;
  int x  = t / (NN/4);
  int n4 = t - x*(NN/4);
  int4 rp = ((const int4*)row_ptr)[n4];
  int4 c  = ((int4*)(cnt16 + (size_t)x*NN))[n4];
  c.x += rp.x; c.y += rp.y; c.z += rp.z; c.w += rp.w;
  ((int4*)(cnt16 + (size_t)x*NN))[n4] = c;
}

// ---------------- fused: embed+PQR0 (blocks 0..EMB_B) || fill (rest) ----------------
__global__ __launch_bounds__(256) void fill_embed_kernel(
    const int* __restrict__ ei,
    const int* __restrict__ rank, const int* __restrict__ base16,
    int* __restrict__ csr,
    const float* __restrict__ x,
    const float* __restrict__ W1, const float* __restrict__ b1,
    const float* __restrict__ g1, const float* __restrict__ bb1,
    const float* __restrict__ W2, const float* __restrict__ b2,
    const float* __restrict__ g2, const float* __restrict__ bb2,
    const float* __restrict__ Wm, const float* __restrict__ bm,
    const float* __restrict__ Wu, const float* __restrict__ bu,
    const float* __restrict__ fb1, const float* __restrict__ fbng, const float* __restrict__ fbnb,
    float* __restrict__ h, float* __restrict__ pre,
    float* __restrict__ P, _Float16* __restrict__ Qh, float* __restrict__ R,
    float* __restrict__ cvec)
{
  if(blockIdx.x >= EMB_B){
    int t = (blockIdx.x - EMB_B)*256 + threadIdx.x;
    if(t < NE/4){
      int4 d  = ((const int4*)(ei + NE))[t];
      int4 sv = ((const int4*)ei)[t];
      int4 rk = ((const int4*)rank)[t];
      csr[base16[(size_t)((unsigned)rk.x>>20)*NN + d.x] + (rk.x & 0xFFFFF)] = sv.x;
      csr[base16[(size_t)((unsigned)rk.y>>20)*NN + d.y] + (rk.y & 0xFFFFF)] = sv.y;
      csr[base16[(size_t)((unsigned)rk.z>>20)*NN + d.z] + (rk.z & 0xFFFFF)] = sv.z;
      csr[base16[(size_t)((unsigned)rk.w>>20)*NN + d.w] + (rk.w & 0xFFFFF)] = sv.w;
    }
    return;
  }
  int t = blockIdx.x*256 + threadIdx.x;
  const float rs = rsqrtf(1.0f + LN_EPS);
  if(t < 64) cvec[t] = fmaf(fb1[t], fbng[t]*rs, fbnb[t]);
  int n = t >> 2, q = t & 3;
  if(n >= NN) return;
  int base = threadIdx.x & 60;
  float4 xq = ((const float4*)x)[n*4 + q];
  float xv[16];
  #pragma unroll
  for(int m=0;m<4;m++){
    xv[4*m+0]=__shfl(xq.x, base|m);
    xv[4*m+1]=__shfl(xq.y, base|m);
    xv[4*m+2]=__shfl(xq.z, base|m);
    xv[4*m+3]=__shfl(xq.w, base|m);
  }
  float a1q[16]; ld16(b1 + q*16, a1q);
  #pragma unroll
  for(int k=0;k<16;k++){
    float w[16]; ld16(W1 + k*64 + q*16, w);
    float xk = xv[k];
    #pragma unroll
    for(int j=0;j<16;j++) a1q[j] += xk * w[j];
  }
  { float g[16], b[16]; ld16(g1+q*16,g); ld16(bb1+q*16,b);
    #pragma unroll
    for(int j=0;j<16;j++) a1q[j] = gelu_f(a1q[j]*(g[j]*rs) + b[j]); }
  float hq[8]; ld8(b2 + q*8, hq);
  #pragma unroll
  for(int m=0;m<4;m++){
    #pragma unroll
    for(int kk=0;kk<16;kk++){
      float a = __shfl(a1q[kk], base|m);
      float w[8]; ld8(W2 + (m*16+kk)*32 + q*8, w);
      #pragma unroll
      for(int j=0;j<8;j++) hq[j] += a * w[j];
    }
  }
  { float g[8], b[8]; ld8(g2+q*8,g); ld8(bb2+q*8,b);
    #pragma unroll
    for(int j=0;j<8;j++) hq[j] = gelu_f(hq[j]*(g[j]*rs) + b[j]); }
  st8(h   + (size_t)n*32 + q*8, hq);
  st8(pre + (size_t)n*32 + q*8, hq);
  float apv[8], aqv[8], arv[8];
  ld8(bm+q*8, apv); ld8(bu+q*8, arv);
  #pragma unroll
  for(int j=0;j<8;j++) aqv[j]=0.f;
  #pragma unroll
  for(int m=0;m<4;m++){
    #pragma unroll
    for(int kk=0;kk<8;kk++){
      float hk = __shfl(hq[kk], base|m);
      int k = m*8+kk;
      float wm[8],wq[8],wu[8];
      ld8(Wm + k*32      + q*8, wm);
      ld8(Wm + (32+k)*32 + q*8, wq);
      ld8(Wu + k*32      + q*8, wu);
      #pragma unroll
      for(int j=0;j<8;j++){ apv[j]+=hk*wm[j]; aqv[j]+=hk*wq[j]; arv[j]+=hk*wu[j]; }
    }
  }
  st8(P + (size_t)n*32 + q*8, apv);
  st8(R + (size_t)n*32 + q*8, arv);
  half8 qo;
  #pragma unroll
  for(int k=0;k<8;k++) qo[k] = (_Float16)aqv[k];
  *(half8*)(Qh + (size_t)n*32 + q*8) = qo;
}

// -------- message+aggregate: 8 slots x 4q = 32 lanes/node, 2-deep csr prefetch --------
__global__ __launch_bounds__(256) void msg_kernel(
    const float* __restrict__ P, const _Float16* __restrict__ Qh,
    const int* __restrict__ row_ptr, const int* __restrict__ csr_src,
    const float* __restrict__ mg, const float* __restrict__ mb,
    float* __restrict__ aggO)
{
  int tid = blockIdx.x*256 + threadIdx.x;   // grid = NN*32 exactly
  int n = tid >> 5;
  int s = tid & 31;
  int slot = s >> 2;   // 0..7
  int q = s & 3;
  float mgq[8], mbq[8], p8[8];
  ld8(mg + q*8, mgq); ld8(mb + q*8, mbq);
  ld8(P + (size_t)n*32 + q*8, p8);
  float agg8[8] = {0,0,0,0,0,0,0,0};
  int e0 = row_ptr[n], e1 = row_ptr[n+1];
  int e  = e0 + slot;
  int e2 = e + 8;
  int src  = (e  < e1) ? csr_src[e]  : 0;
  int src2 = (e2 < e1) ? csr_src[e2] : 0;
  half8 qv = *(const half8*)(Qh + (size_t)src*32 + q*8);
  while(e < e1){
    half8 qv2 = *(const half8*)(Qh + (size_t)src2*32 + q*8);  // Q prefetch (addr known)
    int e3 = e2 + 8;
    int src3 = (e3 < e1) ? csr_src[e3] : 0;                    // csr prefetch 2-deep
    float v[8];
    #pragma unroll
    for(int k=0;k<8;k++) v[k] = p8[k] + (float)qv[k];
    float ps = ((v[0]+v[1])+(v[2]+v[3])) + ((v[4]+v[5])+(v[6]+v[7]));
    ps += __shfl_xor(ps,1); ps += __shfl_xor(ps,2);
    float mean = ps * 0.03125f;
    float vs = 0.f;
    #pragma unroll
    for(int k=0;k<8;k++){ float dd = v[k]-mean; vs += dd*dd; v[k]=dd; }
    vs += __shfl_xor(vs,1); vs += __shfl_xor(vs,2);
    float rstd = rsqrtf(vs*0.03125f + LN_EPS);
    #pragma unroll
    for(int k=0;k<8;k++) agg8[k] += gelu_f(v[k]*rstd*mgq[k] + mbq[k]);
    qv = qv2; src2 = src3; e = e2; e2 = e3;
  }
  #pragma unroll
  for(int k=0;k<8;k++) agg8[k] += __shfl_xor(agg8[k], 4);
  #pragma unroll
  for(int k=0;k<8;k++) agg8[k] += __shfl_xor(agg8[k], 8);
  #pragma unroll
  for(int k=0;k<8;k++) agg8[k] += __shfl_xor(agg8[k], 16);
  if(slot==0) st8(aggO + (size_t)n*32 + q*8, agg8);
}

// -------- update MLP + next-layer PQR, 4 lanes/node --------
__global__ __launch_bounds__(256) void upd_pqr_kernel(
    const float* __restrict__ aggI, const float* __restrict__ Rio,
    const float* __restrict__ Ub,
    const float* __restrict__ ug, const float* __restrict__ ub,
    const float* __restrict__ Wm2, const float* __restrict__ bm2,
    const float* __restrict__ Wu2, const float* __restrict__ bu2,
    float* __restrict__ h,
    float* __restrict__ P, _Float16* __restrict__ Qh, float* __restrict__ Rout)
{
  int t = blockIdx.x*256 + threadIdx.x;
  int n = t >> 2, q = t & 3;
  if(n >= NN) return;
  int base = threadIdx.x & 60;
  float aggq[8], uq[8];
  ld8(aggI + (size_t)n*32 + q*8, aggq);
  ld8(Rio  + (size_t)n*32 + q*8, uq);
  #pragma unroll
  for(int m=0;m<4;m++){
    #pragma unroll
    for(int kk=0;kk<8;kk++){
      float a = __shfl(aggq[kk], base|m);
      float w[8]; ld8(Ub + (m*8+kk)*32 + q*8, w);
      #pragma unroll
      for(int j=0;j<8;j++) uq[j] += a * w[j];
    }
  }
  float sm = ((uq[0]+uq[1])+(uq[2]+uq[3])) + ((uq[4]+uq[5])+(uq[6]+uq[7]));
  sm += __shfl_xor(sm,1); sm += __shfl_xor(sm,2);
  float mean = sm * 0.03125f;
  float vs = 0.f;
  #pragma unroll
  for(int j=0;j<8;j++){ float d = uq[j]-mean; vs += d*d; uq[j]=d; }
  vs += __shfl_xor(vs,1); vs += __shfl_xor(vs,2);
  float rstd = rsqrtf(vs*0.03125f + LN_EPS);
  float ugq[8], ubq[8], hq[8];
  ld8(ug+q*8, ugq); ld8(ub+q*8, ubq);
  ld8(h + (size_t)n*32 + q*8, hq);
  #pragma unroll
  for(int j=0;j<8;j++) hq[j] += gelu_f(uq[j]*rstd*ugq[j] + ubq[j]);
  st8(h + (size_t)n*32 + q*8, hq);
  // next-layer PQR
  float apv[8], aqv[8], arv[8];
  ld8(bm2+q*8, apv); ld8(bu2+q*8, arv);
  #pragma unroll
  for(int j=0;j<8;j++) aqv[j]=0.f;
  #pragma unroll
  for(int m=0;m<4;m++){
    #pragma unroll
    for(int kk=0;kk<8;kk++){
      float hk = __shfl(hq[kk], base|m);
      int k = m*8+kk;
      float wm[8],wq[8],wu[8];
      ld8(Wm2 + k*32      + q*8, wm);
      ld8(Wm2 + (32+k)*32 + q*8, wq);
      ld8(Wu2 + k*32      + q*8, wu);
      #pragma unroll
      for(int j=0;j<8;j++){ apv[j]+=hk*wm[j]; aqv[j]+=hk*wq[j]; arv[j]+=hk*wu[j]; }
    }
  }
  st8(P    + (size_t)n*32 + q*8, apv);
  st8(Rout + (size_t)n*32 + q*8, arv);
  half8 qo;
  #pragma unroll
  for(int k=0;k<8;k++) qo[k] = (_Float16)aqv[k];
  *(half8*)(Qh + (size_t)n*32 + q*8) = qo;
}

// -------- last update + final node matmul, 4 lanes/node, split-half fp16 y --------
__global__ __launch_bounds__(256) void upd_fin_kernel(
    const float* __restrict__ aggI, const float* __restrict__ Rio,
    const float* __restrict__ Ub,
    const float* __restrict__ ug, const float* __restrict__ ub,
    const float* __restrict__ h, const float* __restrict__ pre,
    const float* __restrict__ fW1, const float* __restrict__ fbng,
    _Float16* __restrict__ y1, _Float16* __restrict__ y2)
{
  int t = blockIdx.x*256 + threadIdx.x;
  int n = t >> 2, q = t & 3;
  if(n >= NN) return;
  int base = threadIdx.x & 60;
  const float rs = rsqrtf(1.0f + LN_EPS);
  float aggq[8], uq[8];
  ld8(aggI + (size_t)n*32 + q*8, aggq);
  ld8(Rio  + (size_t)n*32 + q*8, uq);
  #pragma unroll
  for(int m=0;m<4;m++){
    #pragma unroll
    for(int kk=0;kk<8;kk++){
      float a = __shfl(aggq[kk], base|m);
      float w[8]; ld8(Ub + (m*8+kk)*32 + q*8, w);
      #pragma unroll
      for(int j=0;j<8;j++) uq[j] += a * w[j];
    }
  }
  float sm = ((uq[0]+uq[1])+(uq[2]+uq[3])) + ((uq[4]+uq[5])+(uq[6]+uq[7]));
  sm += __shfl_xor(sm,1); sm += __shfl_xor(sm,2);
  float mean = sm * 0.03125f;
  float vs = 0.f;
  #pragma unroll
  for(int j=0;j<8;j++){ float d = uq[j]-mean; vs += d*d; uq[j]=d; }
  vs += __shfl_xor(vs,1); vs += __shfl_xor(vs,2);
  float rstd = rsqrtf(vs*0.03125f + LN_EPS);
  float ugq[8], ubq[8], hq[8], pq[8];
  ld8(ug+q*8, ugq); ld8(ub+q*8, ubq);
  ld8(h   + (size_t)n*32 + q*8, hq);
  ld8(pre + (size_t)n*32 + q*8, pq);
  #pragma unroll
  for(int j=0;j<8;j++) hq[j] += gelu_f(uq[j]*rstd*ugq[j] + ubq[j]) + pq[j];
  float acc[16];
  #pragma unroll
  for(int j=0;j<16;j++) acc[j]=0.f;
  #pragma unroll
  for(int m=0;m<4;m++){
    #pragma unroll
    for(int kk=0;kk<8;kk++){
      float hk = __shfl(hq[kk], base|m);
      float w[16]; ld16(fW1 + (m*8+kk)*64 + q*16, w);
      #pragma unroll
      for(int j=0;j<16;j++) acc[j] += hk * w[j];
    }
  }
  float fg[16]; ld16(fbng + q*16, fg);
  half8 o0, o1;
  #pragma unroll
  for(int k=0;k<8;k++){
    o0[k] = (_Float16)(acc[k]   * (fg[k]*rs));
    o1[k] = (_Float16)(acc[8+k] * (fg[8+k]*rs));
  }
  _Float16* dst = (q<2) ? (y1 + (size_t)n*32 + q*16) : (y2 + (size_t)n*32 + (q-2)*16);
  ((half8*)dst)[0] = o0; ((half8*)dst)[1] = o1;
}

// ---------------- final per-edge: 4 lanes per edge, 2 edges/group, feature-split ----------------
__global__ __launch_bounds__(256) void finalA_kernel(
    const _Float16* __restrict__ y, const int* __restrict__ ei,
    const float* __restrict__ cvec, const float* __restrict__ W2,
    const float* __restrict__ b2, float* __restrict__ out)
{
  int t = blockIdx.x*256 + threadIdx.x;   // grid = NE*2 exactly
  int g = t >> 2, q = t & 3;
  int eA = g, eB = g + NE/2;
  int sA = __builtin_nontemporal_load(ei + eA);
  int dA = __builtin_nontemporal_load(ei + NE + eA);
  int sB = __builtin_nontemporal_load(ei + eB);
  int dB = __builtin_nontemporal_load(ei + NE + eB);
  half8 aA = *(const half8*)(y + (size_t)dA*32 + q*8);
  half8 cA = *(const half8*)(y + (size_t)sA*32 + q*8);
  half8 aB = *(const half8*)(y + (size_t)dB*32 + q*8);
  half8 cB = *(const half8*)(y + (size_t)sB*32 + q*8);
  float cq[8]; ld8(cvec + q*8, cq);
  float w[24]; ld8(W2+q*24, w); ld8(W2+q*24+8, w+8); ld8(W2+q*24+16, w+16);
  float oA0=0.f,oA1=0.f,oA2=0.f, oB0=0.f,oB1=0.f,oB2=0.f;
  #pragma unroll
  for(int k=0;k<8;k++){
    float tA = gelu_f(((float)aA[k]-(float)cA[k]) + cq[k]);
    float tB = gelu_f(((float)aB[k]-(float)cB[k]) + cq[k]);
    oA0 += tA*w[3*k]; oA1 += tA*w[3*k+1]; oA2 += tA*w[3*k+2];
    oB0 += tB*w[3*k]; oB1 += tB*w[3*k+1]; oB2 += tB*w[3*k+2];
  }
  oA0 += __shfl_xor(oA0,1); oA0 += __shfl_xor(oA0,2);
  oA1 += __shfl_xor(oA1,1); oA1 += __shfl_xor(oA1,2);
  oA2 += __shfl_xor(oA2,1); oA2 += __shfl_xor(oA2,2);
  oB0 += __shfl_xor(oB0,1); oB0 += __shfl_xor(oB0,2);
  oB1 += __shfl_xor(oB1,1); oB1 += __shfl_xor(oB1,2);
  oB2 += __shfl_xor(oB2,1); oB2 += __shfl_xor(oB2,2);
  float ovA = (q==0) ? oA0 + b2[0] : (q==1) ? oA1 + b2[1] : oA2 + b2[2];
  float ovB = (q==0) ? oB0 + b2[0] : (q==1) ? oB1 + b2[1] : oB2 + b2[2];
  if(q < 3){
    __builtin_nontemporal_store(ovA, out + (size_t)eA*3 + q);
    __builtin_nontemporal_store(ovB, out + (size_t)eB*3 + q);
  }
}

__global__ __launch_bounds__(256) void finalB_kernel(
    const _Float16* __restrict__ y, const int* __restrict__ ei,
    const float* __restrict__ cvec, const float* __restrict__ W2,
    float* __restrict__ out)
{
  int t = blockIdx.x*256 + threadIdx.x;
  int g = t >> 2, q = t & 3;
  int eA = g, eB = g + NE/2;
  float pA = 0.f, pB = 0.f;
  if(q < 3){
    pA = __builtin_nontemporal_load(out + (size_t)eA*3 + q);
    pB = __builtin_nontemporal_load(out + (size_t)eB*3 + q);
  }
  int sA = __builtin_nontemporal_load(ei + eA);
  int dA = __builtin_nontemporal_load(ei + NE + eA);
  int sB = __builtin_nontemporal_load(ei + eB);
  int dB = __builtin_nontemporal_load(ei + NE + eB);
  half8 aA = *(const half8*)(y + (size_t)dA*32 + q*8);
  half8 cA = *(const half8*)(y + (size_t)sA*32 + q*8);
  half8 aB = *(const half8*)(y + (size_t)dB*32 + q*8);
  half8 cB = *(const half8*)(y + (size_t)sB*32 + q*8);
  float cq[8]; ld8(cvec + q*8, cq);
  float w[24]; ld8(W2+q*24, w); ld8(W2+q*24+8, w+8); ld8(W2+q*24+16, w+16);
  float oA0=0.f,oA1=0.f,oA2=0.f, oB0=0.f,oB1=0.f,oB2=0.f;
  #pragma unroll
  for(int k=0;k<8;k++){
    float tA = gelu_f(((float)aA[k]-(float)cA[k]) + cq[k]);
    float tB = gelu_f(((float)aB[k]-(float)cB[k]) + cq[k]);
    oA0 += tA*w[3*k]; oA1 += tA*w[3*k+1]; oA2 += tA*w[3*k+2];
    oB0 += tB*w[3*k]; oB1 += tB*w[3*k+1]; oB2 += tB*w[3*k+2];
  }
  oA0 += __shfl_xor(oA0,1); oA0 += __shfl_xor(oA0,2);
  oA1 += __shfl_xor(oA1,1); oA1 += __shfl_xor(oA1,2);
  oA2 += __shfl_xor(oA2,1); oA2 += __shfl_xor(oA2,2);
  oB0 += __shfl_xor(oB0,1); oB0 += __shfl_xor(oB0,2);
  oB1 += __shfl_xor(oB1,1); oB1 += __shfl_xor(oB1,2);
  oB2 += __shfl_xor(oB2,1); oB2 += __shfl_xor(oB2,2);
  float ovA = pA + ((q==0) ? oA0 : (q==1) ? oA1 : oA2);
  float ovB = pB + ((q==0) ? oB0 : (q==1) ? oB1 : oB2);
  if(q < 3){
    __builtin_nontemporal_store(ovA, out + (size_t)eA*3 + q);
    __builtin_nontemporal_store(ovB, out + (size_t)eB*3 + q);
  }
}

extern "C" void kernel_launch(void* const* d_in, const int* in_sizes, int n_in,
                              void* d_out, int out_size, void* d_ws, size_t ws_size,
                              hipStream_t stream)
{
  (void)in_sizes; (void)n_in; (void)out_size; (void)ws_size;
  const float* x     = (const float*)d_in[0];
  const int*   ei    = (const int*)d_in[1];
  const float* eW1   = (const float*)d_in[2];
  const float* eb1   = (const float*)d_in[3];
  const float* ebn1g = (const float*)d_in[4];
  const float* ebn1b = (const float*)d_in[5];
  const float* eW2   = (const float*)d_in[6];
  const float* eb2   = (const float*)d_in[7];
  const float* ebn2g = (const float*)d_in[8];
  const float* ebn2b = (const float*)d_in[9];
  const float* msgW  = (const float*)d_in[10];
  const float* msgb  = (const float*)d_in[11];
  const float* msglng= (const float*)d_in[12];
  const float* msglnb= (const float*)d_in[13];
  const float* updW  = (const float*)d_in[14];
  const float* updb  = (const float*)d_in[15];
  const float* updlng= (const float*)d_in[16];
  const float* updlnb= (const float*)d_in[17];
  const float* fW1   = (const float*)d_in[18];
  const float* fb1   = (const float*)d_in[19];
  const float* fbng  = (const float*)d_in[20];
  const float* fbnb  = (const float*)d_in[21];
  const float* fW2   = (const float*)d_in[22];
  const float* fb2   = (const float*)d_in[23];
  float* out = (float*)d_out;

  // workspace: h, pre, P, R, agg (NN*32 f32 each), Qh (NN*16 f32), cvec, ints
  float* f   = (float*)d_ws;
  float* h   = f;
  float* pre = f + 1*(size_t)NN*32;
  float* P   = f + 2*(size_t)NN*32;
  float* R   = f + 3*(size_t)NN*32;
  float* agg = f + 4*(size_t)NN*32;
  _Float16* Qh = (_Float16*)(f + 5*(size_t)NN*32);   // NN*32 halves
  _Float16* y1 = (_Float16*)P;                        // NN*32 halves (P dead after msg2)
  _Float16* y2 = y1 + (size_t)NN*32;                  // NN*32 halves (still within P)
  float* cvec  = f + 5*(size_t)NN*32 + (size_t)NN*16; // 64 floats
  int* ip      = (int*)(cvec + 64);
  int* cnt16   = ip;                  // 16*NN (shard-prefix, then base16 after addbase16)
  int* deg     = ip + 16*NN;          // NN
  int* row_ptr = ip + 17*NN;          // NN+4
  int* csr     = ip + 18*NN + 4;      // NE
  int* rank    = (int*)agg;           // NE ints, aliases agg (free until msg layer 0)

  hipMemsetAsync(cnt16, 0, (size_t)16*NN*sizeof(int), stream);
  hist_kernel<<<391, 256, 0, stream>>>(ei, cnt16, rank);
  reduce16_kernel<<<(NN+255)/256, 256, 0, stream>>>(cnt16, deg);
  scan_kernel<<<1, 1024, 0, stream>>>(deg, row_ptr);
  addbase16_kernel<<<(16*(NN/4)+255)/256, 256, 0, stream>>>(cnt16, row_ptr);
  fill_embed_kernel<<<EMB_B + FILL_B, 256, 0, stream>>>(ei, rank, cnt16, csr,
      x, eW1, eb1, ebn1g, ebn1b,
      eW2, eb2, ebn2g, ebn2b,
      msgW, msgb, updW, updb,
      fb1, fbng, fbnb,
      h, pre, P, Qh, R, cvec);

  for(int l=0; l<3; l++){
    msg_kernel<<<(NN*32)/256, 256, 0, stream>>>(P, Qh, row_ptr, csr,
        msglng + l*32, msglnb + l*32, agg);
    if(l < 2){
      upd_pqr_kernel<<<EMB_B, 256, 0, stream>>>(agg, R,
          updW + l*2048 + 1024, updlng + l*32, updlnb + l*32,
          msgW + (l+1)*2048, msgb + (l+1)*32,
          updW + (l+1)*2048, updb + (l+1)*32,
          h, P, Qh, R);
    } else {
      upd_fin_kernel<<<EMB_B, 256, 0, stream>>>(agg, R,
          updW + l*2048 + 1024, updlng + l*32, updlnb + l*32,
          h, pre, fW1, fbng, y1, y2);
    }
  }

  finalA_kernel<<<(NE*2)/256, 256, 0, stream>>>(y1, ei, cvec,      fW2,      fb2, out);
  finalB_kernel<<<(NE*2)/256, 256, 0, stream>>>(y2, ei, cvec + 32, fW2 + 96, out);
}